// Round 1
// baseline (26966.531 us; speedup 1.0000x reference)
//
#include <hip/hip_runtime.h>
#include <hip/hip_bf16.h>
#include <stdint.h>

typedef unsigned int u32;
typedef unsigned short u16;
typedef short bf16x8 __attribute__((ext_vector_type(8)));
typedef float f32x4 __attribute__((ext_vector_type(4)));

#define T_STEPS 1024
#define BATCH   64
#define DIM     1024
#define NWG     64      // one WG per 16 hidden columns
#define NTHR    512     // 8 waves
#define NMAT    3       // z, r, h
#define KSLICE  256     // K per wave (waves 0-3: x-part, 4-7: h-part)
#define DCOLS   16      // hidden columns per WG

// round-to-nearest-even f32 -> bf16 bits
__device__ __forceinline__ u16 f2bf(float f) {
  u32 u = __float_as_uint(f);
  return (u16)((u + 0x7FFFu + ((u >> 16) & 1u)) >> 16);
}
__device__ __forceinline__ float sigm(float x) { return 1.0f / (1.0f + __expf(-x)); }
__device__ __forceinline__ float tanh_f(float x) {
  x = fminf(8.0f, fmaxf(-8.0f, x));
  float e = __expf(2.0f * x);
  return (e - 1.0f) / (e + 1.0f);
}

// ---------------- init: zero barrier counters ----------------
__global__ void gru_init(u32* ctr) {
  ctr[threadIdx.x] = 0;   // 1024 threads, 4KB region
}

// ---------------- pack weights into per-wave register-fragment order ----------------
// linear u16 index = ((((wg*8+wv)*3 + n)*8 + ks)*64 + lane)*8 + j
// k = (wv&3)*256 + ks*32 + (lane>>4)*8 + j   (contiguous-8 kappa; A-loads use the SAME kappa,
//                                             so any bijection is correct: MFMA pairs A/B slots)
// col = wg*16 + (lane&15)
__global__ void gru_pack(const float* __restrict__ Wxz, const float* __restrict__ Whz,
                         const float* __restrict__ Wxr, const float* __restrict__ Whr,
                         const float* __restrict__ Wxh, const float* __restrict__ Whh,
                         u16* __restrict__ wpack) {
  int idx = blockIdx.x * 256 + threadIdx.x;
  if (idx >= NWG * 8 * NMAT * 8 * 64) return;
  int lane = idx & 63; int rest = idx >> 6;
  int ks = rest & 7;  rest >>= 3;
  int n  = rest % NMAT; rest /= NMAT;
  int wv = rest & 7;  int wg = rest >> 3;
  int d  = wg * DCOLS + (lane & 15);
  int k0 = (wv & 3) * KSLICE + ks * 32 + (lane >> 4) * 8;
  const float* W = (wv < 4) ? ((n == 0) ? Wxz : (n == 1) ? Wxr : Wxh)
                            : ((n == 0) ? Whz : (n == 1) ? Whr : Whh);
  u16* dst = wpack + (size_t)idx * 8;
#pragma unroll
  for (int j = 0; j < 8; ++j)
    dst[j] = f2bf(W[(size_t)(k0 + j) * DIM + d]);
}

// ---------------- persistent scan kernel ----------------
// 64 WGs x 512 threads. Wave wv holds W[(wv&3)*256 .. +256) x 48 cols in VGPRs.
// Waves 0-3: x-part partials (no barrier dependence). Waves 4-7: poll global barrier,
// load H(t-1) with agent-scope atomic loads (bypass stale L1/L2 -> no cache-inv fences),
// MFMA h-part partials. LDS reduce -> gates -> H_new: f32 kept in registers per thread,
// bf16 copy published with agent-scope atomic stores, then striped-counter arrive.
__launch_bounds__(NTHR, 2)
__global__ void gru_scan(const float* __restrict__ inputs,
                         const float* __restrict__ bz, const float* __restrict__ br,
                         const float* __restrict__ bh,
                         const u16* __restrict__ wpack,
                         u16* hglob, u32* ctr, float* __restrict__ out) {
  __shared__ float part[8][4][NMAT][16][17];   // 102KB, padded to break bank conflicts

  const int tid  = threadIdx.x;
  const int wg   = blockIdx.x;
  const int wv   = tid >> 6;
  const int lane = tid & 63;
  const int isH  = (wv >= 4);
  const int arow = lane & 15;
  const int akoff = (lane >> 4) * 8;

  // persistent B fragments: 24 x bf16x8 = 96 VGPRs (statically indexed only)
  bf16x8 breg[NMAT][8];
  {
    const u16* wp = wpack + ((size_t)(wg * 8 + wv) * NMAT * 8 * 64) * 8;
#pragma unroll
    for (int n = 0; n < NMAT; ++n)
#pragma unroll
      for (int ks = 0; ks < 8; ++ks)
        breg[n][ks] = *(const bf16x8*)(wp + ((n * 8 + ks) * 64 + lane) * 8);
  }

  // elementwise ownership: thread -> (batch row, 2 adjacent d-columns)
  const int erow = tid >> 3;
  const int ep   = tid & 7;
  const int dbase = wg * DCOLS;
  const int d0 = dbase + 2 * ep;
  const float bz0 = bz[d0], bz1 = bz[d0 + 1];
  const float br0 = br[d0], br1 = br[d0 + 1];
  const float bh0 = bh[d0], bh1 = bh[d0 + 1];
  const int em = erow >> 4, er = erow & 15;
  float hp0 = 0.f, hp1 = 0.f;          // H_prev kept in f32 registers

  u32* hg32 = (u32*)hglob;

#pragma unroll 1
  for (int t = 0; t < T_STEPS; ++t) {
    f32x4 acc[4][NMAT];
#pragma unroll
    for (int m = 0; m < 4; ++m)
#pragma unroll
      for (int n = 0; n < NMAT; ++n)
        acc[m][n] = (f32x4){0.f, 0.f, 0.f, 0.f};

    if (!isH) {
      // ---- x-part GEMM: A from inputs[t] (f32 -> bf16 on the fly) ----
      const float* xp = inputs + (size_t)t * (BATCH * DIM) + wv * KSLICE + akoff;
#pragma unroll
      for (int ks = 0; ks < 8; ++ks) {
        bf16x8 a[4];
#pragma unroll
        for (int m = 0; m < 4; ++m) {
          const float* s = xp + (size_t)(m * 16 + arow) * DIM + ks * 32;
          f32x4 lo = *(const f32x4*)s;
          f32x4 hi = *(const f32x4*)(s + 4);
          bf16x8 av;
          av[0] = (short)f2bf(lo[0]); av[1] = (short)f2bf(lo[1]);
          av[2] = (short)f2bf(lo[2]); av[3] = (short)f2bf(lo[3]);
          av[4] = (short)f2bf(hi[0]); av[5] = (short)f2bf(hi[1]);
          av[6] = (short)f2bf(hi[2]); av[7] = (short)f2bf(hi[3]);
          a[m] = av;
        }
#pragma unroll
        for (int m = 0; m < 4; ++m)
#pragma unroll
          for (int n = 0; n < NMAT; ++n)
            acc[m][n] = __builtin_amdgcn_mfma_f32_16x16x32_bf16(a[m], breg[n][ks], acc[m][n], 0, 0, 0);
      }
    } else if (t > 0) {
      // ---- wait for all WGs to publish H(t-1) ----
      const u32 target = (u32)t * 8u;   // 8 WGs arrive per striped counter per step
      for (;;) {
        u32 c = 0xFFFFFFFFu;
        if (lane < 8) c = __hip_atomic_load(ctr + lane * 16, __ATOMIC_RELAXED, __HIP_MEMORY_SCOPE_AGENT);
        if (__all((lane < 8) ? (int)(c >= target) : 1)) break;
        __builtin_amdgcn_s_sleep(1);
      }
      asm volatile("" ::: "memory");
      // ---- h-part GEMM: A from H(t-1), coherent loads ----
      u32* hpb = hg32 + (size_t)((t - 1) & 1) * (BATCH * DIM / 2)
                      + (((wv - 4) * KSLICE + akoff) >> 1);
#pragma unroll
      for (int ks = 0; ks < 8; ++ks) {
        bf16x8 a[4];
#pragma unroll
        for (int m = 0; m < 4; ++m) {
          u32* s = hpb + (size_t)(m * 16 + arow) * (DIM / 2) + ks * 16;
          union { u32 u[4]; bf16x8 v; } cv;
#pragma unroll
          for (int q = 0; q < 4; ++q)
            cv.u[q] = __hip_atomic_load(s + q, __ATOMIC_RELAXED, __HIP_MEMORY_SCOPE_AGENT);
          a[m] = cv.v;
        }
#pragma unroll
        for (int m = 0; m < 4; ++m)
#pragma unroll
          for (int n = 0; n < NMAT; ++n)
            acc[m][n] = __builtin_amdgcn_mfma_f32_16x16x32_bf16(a[m], breg[n][ks], acc[m][n], 0, 0, 0);
      }
    }
    // (t==0 h-waves: zero partials, H(-1)=0)

    // ---- publish partials to LDS (C/D layout: col=lane&15, row=(lane>>4)*4+reg) ----
    {
      const int c = lane & 15, r0 = (lane >> 4) * 4;
#pragma unroll
      for (int m = 0; m < 4; ++m)
#pragma unroll
        for (int n = 0; n < NMAT; ++n) {
#pragma unroll
          for (int rr = 0; rr < 4; ++rr)
            part[wv][m][n][r0 + rr][c] = acc[m][n][rr];
        }
    }
    __syncthreads();

    // ---- reduce + gates (all 512 threads; 2 outputs each) ----
    float zp = bz0, zq = bz1, rp = br0, rq = br1;
    float xh0 = bh0, xh1 = bh1, hh0 = 0.f, hh1 = 0.f;
#pragma unroll
    for (int w = 0; w < 8; ++w) {
      zp += part[w][em][0][er][2 * ep];
      zq += part[w][em][0][er][2 * ep + 1];
      rp += part[w][em][1][er][2 * ep];
      rq += part[w][em][1][er][2 * ep + 1];
      float h0 = part[w][em][2][er][2 * ep];
      float h1 = part[w][em][2][er][2 * ep + 1];
      if (w < 4) { xh0 += h0; xh1 += h1; }   // x-part of candidate (NOT scaled by R)
      else       { hh0 += h0; hh1 += h1; }   // recurrent part (scaled by R)
    }
    float z0 = sigm(zp), z1 = sigm(zq);
    float r0 = sigm(rp), r1 = sigm(rq);
    float th0 = tanh_f(xh0 + r0 * hh0);
    float th1 = tanh_f(xh1 + r1 * hh1);
    float hn0 = z0 * hp0 + (1.f - z0) * th0;
    float hn1 = z1 * hp1 + (1.f - z1) * th1;
    hp0 = hn0; hp1 = hn1;

    // outputs (f32, normal cached stores)
    float* op = out + (size_t)t * (BATCH * DIM) + (size_t)erow * DIM + d0;
    *(float2*)op = make_float2(hn0, hn1);
    if (t == T_STEPS - 1) {
      float* fp = out + (size_t)T_STEPS * (BATCH * DIM) + (size_t)erow * DIM + d0;
      *(float2*)fp = make_float2(hn0, hn1);
    }
    // publish H(t) as bf16, coherent (double-buffered by step parity)
    u32 pk = ((u32)f2bf(hn1) << 16) | (u32)f2bf(hn0);
    __hip_atomic_store(hg32 + (size_t)(t & 1) * (BATCH * DIM / 2)
                             + (size_t)erow * (DIM / 2) + (dbase >> 1) + ep,
                       pk, __ATOMIC_RELAXED, __HIP_MEMORY_SCOPE_AGENT);

    // all stores globally visible before arrival
    asm volatile("s_waitcnt vmcnt(0)" ::: "memory");
    __syncthreads();
    if (tid == 0)
      __hip_atomic_fetch_add(ctr + (wg & 7) * 16, 1u, __ATOMIC_RELAXED, __HIP_MEMORY_SCOPE_AGENT);
  }
}

extern "C" void kernel_launch(void* const* d_in, const int* in_sizes, int n_in,
                              void* d_out, int out_size, void* d_ws, size_t ws_size,
                              hipStream_t stream) {
  const float* inputs = (const float*)d_in[0];
  const float* Wxz = (const float*)d_in[1];
  const float* Whz = (const float*)d_in[2];
  const float* bz  = (const float*)d_in[3];
  const float* Wxr = (const float*)d_in[4];
  const float* Whr = (const float*)d_in[5];
  const float* br  = (const float*)d_in[6];
  const float* Wxh = (const float*)d_in[7];
  const float* Whh = (const float*)d_in[8];
  const float* bh  = (const float*)d_in[9];
  float* out = (float*)d_out;

  // ws layout: [0,4K) barrier counters | [4K, 4K+256K) H double buffer (bf16)
  //            | [266240, +12.6MB) packed weights
  char* ws = (char*)d_ws;
  u32* ctr   = (u32*)ws;
  u16* hglob = (u16*)(ws + 4096);
  u16* wpack = (u16*)(ws + 4096 + 2 * BATCH * DIM * sizeof(u16));
  if (ws_size < (size_t)(4096 + 2 * BATCH * DIM * 2 + NWG * 8 * NMAT * 8 * 64 * 8 * 2))
    return;  // insufficient workspace: fail visibly (output stays poisoned)

  hipLaunchKernelGGL(gru_init, dim3(1), dim3(1024), 0, stream, ctr);
  const int total = NWG * 8 * NMAT * 8 * 64;
  hipLaunchKernelGGL(gru_pack, dim3((total + 255) / 256), dim3(256), 0, stream,
                     Wxz, Whz, Wxr, Whr, Wxh, Whh, wpack);
  // 64 blocks on 256 CUs: trivially co-resident (persistent kernel with global barrier)
  hipLaunchKernelGGL(gru_scan, dim3(NWG), dim3(NTHR), 0, stream,
                     inputs, bz, br, bh, wpack, hglob, ctr, out);
}

// Round 2
// 18007.324 us; speedup vs baseline: 1.4975x; 1.4975x over previous
//
#include <hip/hip_runtime.h>
#include <hip/hip_bf16.h>
#include <stdint.h>

typedef unsigned int u32;
typedef unsigned short u16;
typedef short bf16x8 __attribute__((ext_vector_type(8)));
typedef float f32x4 __attribute__((ext_vector_type(4)));
typedef u32 u32x4 __attribute__((ext_vector_type(4)));

#define T_STEPS 1024
#define BATCH   64
#define DIM     1024
#define NWG     64      // one WG per 16 hidden columns
#define NTHR    512     // 8 waves
#define NMAT    3       // z, r, h
#define KSLICE  256     // K per wave (waves 0-3: x-part, 4-7: h-part)
#define DCOLS   16      // hidden columns per WG

// round-to-nearest-even f32 -> bf16 bits
__device__ __forceinline__ u16 f2bf(float f) {
  u32 u = __float_as_uint(f);
  return (u16)((u + 0x7FFFu + ((u >> 16) & 1u)) >> 16);
}
__device__ __forceinline__ float sigm(float x) { return 1.0f / (1.0f + __expf(-x)); }
__device__ __forceinline__ float tanh_f(float x) {
  x = fminf(8.0f, fmaxf(-8.0f, x));
  float e = __expf(2.0f * x);
  return (e - 1.0f) / (e + 1.0f);
}

// ---------------- init: zero per-WG barrier flags ----------------
__global__ void gru_init(u32* flags) {
  flags[threadIdx.x] = 0;   // 1024 u32 = 4KB region (64 flags at 64B stride)
}

// ---------------- pack weights into per-wave register-fragment order ----------------
// linear u16 index = ((((wg*8+wv)*3 + n)*8 + ks)*64 + lane)*8 + j
// k = (wv&3)*256 + ks*32 + (lane>>4)*8 + j   (contiguous-8 kappa; A-loads use the SAME kappa)
// col = wg*16 + (lane&15)
__global__ void gru_pack(const float* __restrict__ Wxz, const float* __restrict__ Whz,
                         const float* __restrict__ Wxr, const float* __restrict__ Whr,
                         const float* __restrict__ Wxh, const float* __restrict__ Whh,
                         u16* __restrict__ wpack) {
  int idx = blockIdx.x * 256 + threadIdx.x;
  if (idx >= NWG * 8 * NMAT * 8 * 64) return;
  int lane = idx & 63; int rest = idx >> 6;
  int ks = rest & 7;  rest >>= 3;
  int n  = rest % NMAT; rest /= NMAT;
  int wv = rest & 7;  int wg = rest >> 3;
  int d  = wg * DCOLS + (lane & 15);
  int k0 = (wv & 3) * KSLICE + ks * 32 + (lane >> 4) * 8;
  const float* W = (wv < 4) ? ((n == 0) ? Wxz : (n == 1) ? Wxr : Wxh)
                            : ((n == 0) ? Whz : (n == 1) ? Whr : Whh);
  u16* dst = wpack + (size_t)idx * 8;
#pragma unroll
  for (int j = 0; j < 8; ++j)
    dst[j] = f2bf(W[(size_t)(k0 + j) * DIM + d]);
}

// coherent 16B load with literal byte offset (device-coherent: bypass stale L1/L2)
#define LOADX4(dst, ptr, OFF) \
  asm volatile("global_load_dwordx4 %0, %1, off offset:" #OFF " sc0 sc1" \
               : "=v"(dst) : "v"(ptr))

#define HLOAD(B, pm) \
  LOADX4(B##0, (pm), 0);   LOADX4(B##1, (pm), 64);  LOADX4(B##2, (pm), 128); \
  LOADX4(B##3, (pm), 192); LOADX4(B##4, (pm), 256); LOADX4(B##5, (pm), 320); \
  LOADX4(B##6, (pm), 384); LOADX4(B##7, (pm), 448)

#define MF1(B, ks, m) { bf16x8 _a = __builtin_bit_cast(bf16x8, B); \
  acc[m][0] = __builtin_amdgcn_mfma_f32_16x16x32_bf16(_a, breg[0][ks], acc[m][0], 0, 0, 0); \
  acc[m][1] = __builtin_amdgcn_mfma_f32_16x16x32_bf16(_a, breg[1][ks], acc[m][1], 0, 0, 0); \
  acc[m][2] = __builtin_amdgcn_mfma_f32_16x16x32_bf16(_a, breg[2][ks], acc[m][2], 0, 0, 0); }

#define HMFMA(B, m) \
  MF1(B##0, 0, m); MF1(B##1, 1, m); MF1(B##2, 2, m); MF1(B##3, 3, m); \
  MF1(B##4, 4, m); MF1(B##5, 5, m); MF1(B##6, 6, m); MF1(B##7, 7, m)

#define WAITV(N) \
  asm volatile("s_waitcnt vmcnt(" #N ")" ::: "memory"); \
  __builtin_amdgcn_sched_barrier(0)

// ---------------- persistent scan kernel ----------------
// 64 WGs x 512 threads. Wave wv holds W[(wv&3)*256 .. +256) x 48 cols in VGPRs (asm-pinned).
// Waves 0-3: x-part partials (no barrier dependence, overlap the poll). Waves 4-7: poll
// per-WG flags (read-only, no RMW contention), then pipelined coherent dwordx4 loads of
// H(t-1) with counted vmcnt. LDS reduce -> gates -> publish H(t) coherent -> flag store.
__launch_bounds__(NTHR, 2)
__global__ void gru_scan(const float* __restrict__ inputs,
                         const float* __restrict__ bz, const float* __restrict__ br,
                         const float* __restrict__ bh,
                         const u16* __restrict__ wpack,
                         u16* hglob, u32* flags, float* __restrict__ out) {
  __shared__ float part[8][4][NMAT][16][17];   // 104KB, padded

  const int tid  = threadIdx.x;
  const int wg   = blockIdx.x;
  const int wv   = tid >> 6;
  const int lane = tid & 63;
  const int isH  = (wv >= 4);
  const int arow = lane & 15;
  const int akoff = (lane >> 4) * 8;

  // persistent B fragments: 24 x bf16x8 = 96 VGPRs; asm-laundered so the compiler
  // can neither rematerialize the loads inside the t-loop nor sink them to scratch.
  bf16x8 breg[NMAT][8];
  {
    const u16* wp = wpack + ((size_t)(wg * 8 + wv) * NMAT * 8 * 64) * 8;
#pragma unroll
    for (int n = 0; n < NMAT; ++n)
#pragma unroll
      for (int ks = 0; ks < 8; ++ks) {
        breg[n][ks] = *(const bf16x8*)(wp + ((n * 8 + ks) * 64 + lane) * 8);
        asm volatile("" : "+v"(breg[n][ks]));
      }
  }

  // elementwise ownership: thread -> (batch row, 2 adjacent d-columns)
  const int erow = tid >> 3;
  const int ep   = tid & 7;
  const int dbase = wg * DCOLS;
  const int d0 = dbase + 2 * ep;
  const float bz0 = bz[d0], bz1 = bz[d0 + 1];
  const float br0 = br[d0], br1 = br[d0 + 1];
  const float bh0 = bh[d0], bh1 = bh[d0 + 1];
  const int em = erow >> 4, er = erow & 15;
  float hp0 = 0.f, hp1 = 0.f;          // H_prev kept in f32 registers

  u32* hg32 = (u32*)hglob;

#pragma unroll 1
  for (int t = 0; t < T_STEPS; ++t) {
    f32x4 acc[4][NMAT];
#pragma unroll
    for (int m = 0; m < 4; ++m)
#pragma unroll
      for (int n = 0; n < NMAT; ++n)
        acc[m][n] = (f32x4){0.f, 0.f, 0.f, 0.f};

    if (!isH) {
      // ---- x-part GEMM: A from inputs[t] (f32 -> bf16 on the fly, normal cached loads) ----
      const float* xp = inputs + (size_t)t * (BATCH * DIM) + wv * KSLICE + akoff;
#pragma unroll
      for (int m = 0; m < 4; ++m) {
        const float* rp = xp + (size_t)(m * 16 + arow) * DIM;
#pragma unroll
        for (int ks = 0; ks < 8; ++ks) {
          f32x4 lo = *(const f32x4*)(rp + ks * 32);
          f32x4 hi = *(const f32x4*)(rp + ks * 32 + 4);
          bf16x8 av;
          av[0] = (short)f2bf(lo[0]); av[1] = (short)f2bf(lo[1]);
          av[2] = (short)f2bf(lo[2]); av[3] = (short)f2bf(lo[3]);
          av[4] = (short)f2bf(hi[0]); av[5] = (short)f2bf(hi[1]);
          av[6] = (short)f2bf(hi[2]); av[7] = (short)f2bf(hi[3]);
          MF1(__builtin_bit_cast(u32x4, av), ks, m);
        }
      }
    } else if (t > 0) {
      // ---- wait for all WGs to have published H(t-1): read-only flag poll ----
      const u32* fp = flags + lane * 16;   // 64 flags, 64B stride; lane i polls flag i
      for (;;) {
        u32 f = __hip_atomic_load(fp, __ATOMIC_RELAXED, __HIP_MEMORY_SCOPE_AGENT);
        if (__all((int)(f >= (u32)t))) break;
        __builtin_amdgcn_s_sleep(2);
      }
      asm volatile("" ::: "memory");
      // ---- h-part GEMM: pipelined coherent dwordx4 loads of H(t-1) ----
      const u32* hb = hg32 + (size_t)((t - 1) & 1) * (BATCH * DIM / 2)
                           + (size_t)arow * (DIM / 2) + (wv & 3) * 128 + (lane >> 4) * 4;
      u32x4 hA0, hA1, hA2, hA3, hA4, hA5, hA6, hA7;
      u32x4 hB0, hB1, hB2, hB3, hB4, hB5, hB6, hB7;
      HLOAD(hA, hb);               // m=0 rows
      HLOAD(hB, hb + 8192);        // m=1 rows (16 rows * 512 u32)
      WAITV(8);                    // m0 ready, m1 in flight
      HMFMA(hA, 0);
      HLOAD(hA, hb + 16384);       // m=2
      WAITV(8);                    // m1 ready
      HMFMA(hB, 1);
      HLOAD(hB, hb + 24576);       // m=3
      WAITV(8);                    // m2 ready
      HMFMA(hA, 2);
      WAITV(0);                    // m3 ready
      HMFMA(hB, 3);
    }
    // (t==0 h-waves: zero partials, H(-1)=0)

    // ---- publish partials to LDS (C/D layout: col=lane&15, row=(lane>>4)*4+reg) ----
    {
      const int c = lane & 15, r0 = (lane >> 4) * 4;
#pragma unroll
      for (int m = 0; m < 4; ++m)
#pragma unroll
        for (int n = 0; n < NMAT; ++n) {
#pragma unroll
          for (int rr = 0; rr < 4; ++rr)
            part[wv][m][n][r0 + rr][c] = acc[m][n][rr];
        }
    }
    __syncthreads();

    // ---- reduce + gates (all 512 threads; 2 outputs each) ----
    float zp = bz0, zq = bz1, rp = br0, rq = br1;
    float xh0 = bh0, xh1 = bh1, hh0 = 0.f, hh1 = 0.f;
#pragma unroll
    for (int w = 0; w < 8; ++w) {
      zp += part[w][em][0][er][2 * ep];
      zq += part[w][em][0][er][2 * ep + 1];
      rp += part[w][em][1][er][2 * ep];
      rq += part[w][em][1][er][2 * ep + 1];
      float h0 = part[w][em][2][er][2 * ep];
      float h1 = part[w][em][2][er][2 * ep + 1];
      if (w < 4) { xh0 += h0; xh1 += h1; }   // x-part of candidate (NOT scaled by R)
      else       { hh0 += h0; hh1 += h1; }   // recurrent part (scaled by R)
    }
    float z0 = sigm(zp), z1 = sigm(zq);
    float r0 = sigm(rp), r1 = sigm(rq);
    float th0 = tanh_f(xh0 + r0 * hh0);
    float th1 = tanh_f(xh1 + r1 * hh1);
    float hn0 = z0 * hp0 + (1.f - z0) * th0;
    float hn1 = z1 * hp1 + (1.f - z1) * th1;
    hp0 = hn0; hp1 = hn1;

    // outputs (f32, normal cached stores)
    float* op = out + (size_t)t * (BATCH * DIM) + (size_t)erow * DIM + d0;
    *(float2*)op = make_float2(hn0, hn1);
    if (t == T_STEPS - 1) {
      float* fo = out + (size_t)T_STEPS * (BATCH * DIM) + (size_t)erow * DIM + d0;
      *(float2*)fo = make_float2(hn0, hn1);
    }
    // publish H(t) as bf16, device-coherent store (double-buffered by step parity)
    {
      u32 pk = ((u32)f2bf(hn1) << 16) | (u32)f2bf(hn0);
      u32* hp = hg32 + (size_t)(t & 1) * (BATCH * DIM / 2)
                     + (size_t)erow * (DIM / 2) + (dbase >> 1) + ep;
      asm volatile("global_store_dword %0, %1, off sc0 sc1" :: "v"(hp), "v"(pk) : "memory");
    }

    // all stores globally visible before arrival
    asm volatile("s_waitcnt vmcnt(0)" ::: "memory");
    __syncthreads();
    if (tid == 0) {
      u32* fw = flags + wg * 16;
      u32 tv = (u32)(t + 1);
      asm volatile("global_store_dword %0, %1, off sc0 sc1" :: "v"(fw), "v"(tv) : "memory");
    }
  }
}

extern "C" void kernel_launch(void* const* d_in, const int* in_sizes, int n_in,
                              void* d_out, int out_size, void* d_ws, size_t ws_size,
                              hipStream_t stream) {
  const float* inputs = (const float*)d_in[0];
  const float* Wxz = (const float*)d_in[1];
  const float* Whz = (const float*)d_in[2];
  const float* bz  = (const float*)d_in[3];
  const float* Wxr = (const float*)d_in[4];
  const float* Whr = (const float*)d_in[5];
  const float* br  = (const float*)d_in[6];
  const float* Wxh = (const float*)d_in[7];
  const float* Whh = (const float*)d_in[8];
  const float* bh  = (const float*)d_in[9];
  float* out = (float*)d_out;

  // ws layout: [0,4K) per-WG flags | [4K, 4K+256K) H double buffer (bf16)
  //            | [266240, +12.6MB) packed weights
  char* ws = (char*)d_ws;
  u32* flags = (u32*)ws;
  u16* hglob = (u16*)(ws + 4096);
  u16* wpack = (u16*)(ws + 4096 + 2 * BATCH * DIM * sizeof(u16));
  if (ws_size < (size_t)(4096 + 2 * BATCH * DIM * 2 + NWG * 8 * NMAT * 8 * 64 * 8 * 2))
    return;  // insufficient workspace: fail visibly (output stays poisoned)

  hipLaunchKernelGGL(gru_init, dim3(1), dim3(1024), 0, stream, flags);
  const int total = NWG * 8 * NMAT * 8 * 64;
  hipLaunchKernelGGL(gru_pack, dim3((total + 255) / 256), dim3(256), 0, stream,
                     Wxz, Whz, Wxr, Whr, Wxh, Whh, wpack);
  // 64 blocks on 256 CUs: trivially co-resident (persistent kernel with global barrier)
  hipLaunchKernelGGL(gru_scan, dim3(NWG), dim3(NTHR), 0, stream,
                     inputs, bz, br, bh, wpack, hglob, flags, out);
}

// Round 3
// 11099.079 us; speedup vs baseline: 2.4296x; 1.6224x over previous
//
#include <hip/hip_runtime.h>
#include <hip/hip_bf16.h>
#include <stdint.h>

typedef unsigned int u32;
typedef unsigned short u16;
typedef short bf16x8 __attribute__((ext_vector_type(8)));
typedef float f32x4 __attribute__((ext_vector_type(4)));
typedef u32 u32x4 __attribute__((ext_vector_type(4)));

#define T_STEPS 1024
#define BATCH   64
#define DIM     1024
#define NWG     64      // one WG per 16 hidden columns
#define NTHR    512     // 8 waves
#define NMAT    3       // z, r, h
#define KSLICE  256     // K per wave (waves 0-3: x-part, 4-7: h-part)
#define DCOLS   16      // hidden columns per WG

// round-to-nearest-even f32 -> bf16 bits
__device__ __forceinline__ u16 f2bf(float f) {
  u32 u = __float_as_uint(f);
  return (u16)((u + 0x7FFFu + ((u >> 16) & 1u)) >> 16);
}
__device__ __forceinline__ float sigm(float x) { return 1.0f / (1.0f + __expf(-x)); }
__device__ __forceinline__ float tanh_f(float x) {
  x = fminf(8.0f, fmaxf(-8.0f, x));
  float e = __expf(2.0f * x);
  return (e - 1.0f) / (e + 1.0f);
}

// ---------------- init: zero flags + epoch ----------------
__global__ void gru_init(u32* flags) {
  flags[threadIdx.x] = 0;
  flags[1024 + threadIdx.x] = 0;   // 8KB total: flags region + epoch line
}

// ---------------- one-time input f32 -> bf16 conversion ----------------
__global__ void gru_xconv(const float* __restrict__ in, u32* __restrict__ xb) {
  size_t i = (size_t)(blockIdx.x * 256 + threadIdx.x) * 8;
  f32x4 lo = *(const f32x4*)(in + i);
  f32x4 hi = *(const f32x4*)(in + i + 4);
  u32x4 o;
  o[0] = ((u32)f2bf(lo[1]) << 16) | f2bf(lo[0]);
  o[1] = ((u32)f2bf(lo[3]) << 16) | f2bf(lo[2]);
  o[2] = ((u32)f2bf(hi[1]) << 16) | f2bf(hi[0]);
  o[3] = ((u32)f2bf(hi[3]) << 16) | f2bf(hi[2]);
  *(u32x4*)(xb + i / 2) = o;
}

// ---------------- pack weights into per-wave register-fragment order ----------------
// k = (wv&3)*256 + ks*32 + (lane>>4)*8 + j   (contiguous-8 kappa; A-loads use the SAME kappa)
// col = wg*16 + (lane&15)
__global__ void gru_pack(const float* __restrict__ Wxz, const float* __restrict__ Whz,
                         const float* __restrict__ Wxr, const float* __restrict__ Whr,
                         const float* __restrict__ Wxh, const float* __restrict__ Whh,
                         u16* __restrict__ wpack) {
  int idx = blockIdx.x * 256 + threadIdx.x;
  if (idx >= NWG * 8 * NMAT * 8 * 64) return;
  int lane = idx & 63; int rest = idx >> 6;
  int ks = rest & 7;  rest >>= 3;
  int n  = rest % NMAT; rest /= NMAT;
  int wv = rest & 7;  int wg = rest >> 3;
  int d  = wg * DCOLS + (lane & 15);
  int k0 = (wv & 3) * KSLICE + ks * 32 + (lane >> 4) * 8;
  const float* W = (wv < 4) ? ((n == 0) ? Wxz : (n == 1) ? Wxr : Wxh)
                            : ((n == 0) ? Whz : (n == 1) ? Whr : Whh);
  u16* dst = wpack + (size_t)idx * 8;
#pragma unroll
  for (int j = 0; j < 8; ++j)
    dst[j] = f2bf(W[(size_t)(k0 + j) * DIM + d]);
}

// coherent 16B load with literal byte offset (device-coherent: bypass stale L1/L2)
#define LOADX4(dst, ptr, OFF) \
  asm volatile("global_load_dwordx4 %0, %1, off offset:" #OFF " sc0 sc1" \
               : "=v"(dst) : "v"(ptr))

#define HLOAD(B, pm) \
  LOADX4(B##0, (pm), 0);   LOADX4(B##1, (pm), 64);  LOADX4(B##2, (pm), 128); \
  LOADX4(B##3, (pm), 192); LOADX4(B##4, (pm), 256); LOADX4(B##5, (pm), 320); \
  LOADX4(B##6, (pm), 384); LOADX4(B##7, (pm), 448)

#define MF1(B, ks, m) { bf16x8 _a = __builtin_bit_cast(bf16x8, B); \
  acc[m][0] = __builtin_amdgcn_mfma_f32_16x16x32_bf16(_a, breg[0][ks], acc[m][0], 0, 0, 0); \
  acc[m][1] = __builtin_amdgcn_mfma_f32_16x16x32_bf16(_a, breg[1][ks], acc[m][1], 0, 0, 0); \
  acc[m][2] = __builtin_amdgcn_mfma_f32_16x16x32_bf16(_a, breg[2][ks], acc[m][2], 0, 0, 0); }

#define HMFMA(B, m) \
  MF1(B##0, 0, m); MF1(B##1, 1, m); MF1(B##2, 2, m); MF1(B##3, 3, m); \
  MF1(B##4, 4, m); MF1(B##5, 5, m); MF1(B##6, 6, m); MF1(B##7, 7, m)

#define WAITV(N) \
  asm volatile("s_waitcnt vmcnt(" #N ")" ::: "memory"); \
  __builtin_amdgcn_sched_barrier(0)

// ---------------- persistent scan kernel ----------------
// Epoch barrier: WG0's h-waves poll the 64 per-WG flags (the "clock"); WG0 publishes a
// single epoch word; WGs 1-63 poll ONE uniform address (1 fabric request per wave).
template <bool XB>
__launch_bounds__(NTHR, 2)
__global__ void gru_scan(const float* __restrict__ inputs, const u32* __restrict__ xbf,
                         const float* __restrict__ bz, const float* __restrict__ br,
                         const float* __restrict__ bh,
                         const u16* __restrict__ wpack,
                         u16* hglob, u32* flags, u32* epoch, float* __restrict__ out) {
  __shared__ float part[8][4][NMAT][16][17];   // 104KB, padded

  const int tid  = threadIdx.x;
  const int wg   = blockIdx.x;
  const int wv   = tid >> 6;
  const int lane = tid & 63;
  const int isH  = (wv >= 4);
  const int arow = lane & 15;
  const int akoff = (lane >> 4) * 8;

  // persistent B fragments: 24 x bf16x8; asm-laundered against remat/spill
  bf16x8 breg[NMAT][8];
  {
    const u16* wp = wpack + ((size_t)(wg * 8 + wv) * NMAT * 8 * 64) * 8;
#pragma unroll
    for (int n = 0; n < NMAT; ++n)
#pragma unroll
      for (int ks = 0; ks < 8; ++ks) {
        breg[n][ks] = *(const bf16x8*)(wp + ((n * 8 + ks) * 64 + lane) * 8);
        asm volatile("" : "+v"(breg[n][ks]));
      }
  }

  // elementwise ownership: thread -> (batch row, 2 adjacent d-columns)
  const int erow = tid >> 3;
  const int ep   = tid & 7;
  const int dbase = wg * DCOLS;
  const int d0 = dbase + 2 * ep;
  const float bz0 = bz[d0], bz1 = bz[d0 + 1];
  const float br0 = br[d0], br1 = br[d0 + 1];
  const float bh0 = bh[d0], bh1 = bh[d0 + 1];
  const int em = erow >> 4, er = erow & 15;
  float hp0 = 0.f, hp1 = 0.f;          // H_prev kept in f32 registers

  u32* hg32 = (u32*)hglob;

#pragma unroll 1
  for (int t = 0; t < T_STEPS; ++t) {
    f32x4 acc[4][NMAT];
#pragma unroll
    for (int m = 0; m < 4; ++m)
#pragma unroll
      for (int n = 0; n < NMAT; ++n)
        acc[m][n] = (f32x4){0.f, 0.f, 0.f, 0.f};

    if (!isH) {
      // ---- x-part GEMM ----
      if (XB) {
        const u16* xp = (const u16*)xbf + (size_t)t * (BATCH * DIM) + wv * KSLICE + akoff;
#pragma unroll
        for (int m = 0; m < 4; ++m) {
          const u16* rp = xp + (size_t)(m * 16 + arow) * DIM;
#pragma unroll
          for (int ks = 0; ks < 8; ++ks) {
            bf16x8 av = *(const bf16x8*)(rp + ks * 32);
            MF1(__builtin_bit_cast(u32x4, av), ks, m);
          }
        }
      } else {
        const float* xp = inputs + (size_t)t * (BATCH * DIM) + wv * KSLICE + akoff;
#pragma unroll
        for (int m = 0; m < 4; ++m) {
          const float* rp = xp + (size_t)(m * 16 + arow) * DIM;
#pragma unroll
          for (int ks = 0; ks < 8; ++ks) {
            f32x4 lo = *(const f32x4*)(rp + ks * 32);
            f32x4 hi = *(const f32x4*)(rp + ks * 32 + 4);
            bf16x8 av;
            av[0] = (short)f2bf(lo[0]); av[1] = (short)f2bf(lo[1]);
            av[2] = (short)f2bf(lo[2]); av[3] = (short)f2bf(lo[3]);
            av[4] = (short)f2bf(hi[0]); av[5] = (short)f2bf(hi[1]);
            av[6] = (short)f2bf(hi[2]); av[7] = (short)f2bf(hi[3]);
            MF1(__builtin_bit_cast(u32x4, av), ks, m);
          }
        }
      }
    } else if (t > 0) {
      // ---- barrier wait for H(t-1) ----
      if (wg == 0) {
        const u32* fp = flags + lane * 16;   // 64 flags, 64B stride; lane i polls flag i
        for (;;) {
          u32 f = __hip_atomic_load(fp, __ATOMIC_RELAXED, __HIP_MEMORY_SCOPE_AGENT);
          if (__all((int)(f >= (u32)t))) break;
          __builtin_amdgcn_s_sleep(1);
        }
        if (wv == 4 && lane == 0) {          // publish epoch for everyone else
          u32 tv = (u32)t;
          asm volatile("global_store_dword %0, %1, off sc0 sc1" :: "v"(epoch), "v"(tv) : "memory");
        }
      } else {
        for (;;) {                            // uniform-address poll: 1 request/wave/iter
          u32 e = __hip_atomic_load(epoch, __ATOMIC_RELAXED, __HIP_MEMORY_SCOPE_AGENT);
          if ((int)e >= t) break;
          __builtin_amdgcn_s_sleep(1);
        }
      }
      asm volatile("" ::: "memory");
      // ---- h-part GEMM: pipelined coherent dwordx4 loads of H(t-1) ----
      const u32* hb = hg32 + (size_t)((t - 1) & 1) * (BATCH * DIM / 2)
                           + (size_t)arow * (DIM / 2) + (wv & 3) * 128 + (lane >> 4) * 4;
      u32x4 hA0, hA1, hA2, hA3, hA4, hA5, hA6, hA7;
      u32x4 hB0, hB1, hB2, hB3, hB4, hB5, hB6, hB7;
      HLOAD(hA, hb);               // m=0 rows
      HLOAD(hB, hb + 8192);        // m=1 rows (16 rows * 512 u32)
      WAITV(8);                    // m0 ready, m1 in flight
      HMFMA(hA, 0);
      HLOAD(hA, hb + 16384);       // m=2
      WAITV(8);                    // m1 ready
      HMFMA(hB, 1);
      HLOAD(hB, hb + 24576);       // m=3
      WAITV(8);                    // m2 ready
      HMFMA(hA, 2);
      WAITV(0);                    // m3 ready
      HMFMA(hB, 3);
    }
    // (t==0 h-waves: zero partials, H(-1)=0)

    // ---- publish partials to LDS (C/D layout: col=lane&15, row=(lane>>4)*4+reg) ----
    {
      const int c = lane & 15, r0 = (lane >> 4) * 4;
#pragma unroll
      for (int m = 0; m < 4; ++m)
#pragma unroll
        for (int n = 0; n < NMAT; ++n) {
#pragma unroll
          for (int rr = 0; rr < 4; ++rr)
            part[wv][m][n][r0 + rr][c] = acc[m][n][rr];
        }
    }
    __syncthreads();

    // ---- reduce + gates (all 512 threads; 2 outputs each) ----
    float zp = bz0, zq = bz1, rp = br0, rq = br1;
    float xh0 = bh0, xh1 = bh1, hh0 = 0.f, hh1 = 0.f;
#pragma unroll
    for (int w = 0; w < 8; ++w) {
      zp += part[w][em][0][er][2 * ep];
      zq += part[w][em][0][er][2 * ep + 1];
      rp += part[w][em][1][er][2 * ep];
      rq += part[w][em][1][er][2 * ep + 1];
      float h0 = part[w][em][2][er][2 * ep];
      float h1 = part[w][em][2][er][2 * ep + 1];
      if (w < 4) { xh0 += h0; xh1 += h1; }   // x-part of candidate (NOT scaled by R)
      else       { hh0 += h0; hh1 += h1; }   // recurrent part (scaled by R)
    }
    float z0 = sigm(zp), z1 = sigm(zq);
    float r0 = sigm(rp), r1 = sigm(rq);
    float th0 = tanh_f(xh0 + r0 * hh0);
    float th1 = tanh_f(xh1 + r1 * hh1);
    float hn0 = z0 * hp0 + (1.f - z0) * th0;
    float hn1 = z1 * hp1 + (1.f - z1) * th1;
    hp0 = hn0; hp1 = hn1;

    // publish H(t) as bf16, device-coherent (double-buffered by step parity)
    {
      u32 pk = ((u32)f2bf(hn1) << 16) | (u32)f2bf(hn0);
      u32* hp = hg32 + (size_t)(t & 1) * (BATCH * DIM / 2)
                     + (size_t)erow * (DIM / 2) + (dbase >> 1) + ep;
      asm volatile("global_store_dword %0, %1, off sc0 sc1" :: "v"(hp), "v"(pk) : "memory");
    }
    // drain ONLY what the arrival needs (H store; prior-step out stores long done)
    asm volatile("s_waitcnt vmcnt(0)" ::: "memory");
    __syncthreads();
    if (tid == 0) {
      u32* fw = flags + wg * 16;
      u32 tv = (u32)(t + 1);
      asm volatile("global_store_dword %0, %1, off sc0 sc1" :: "v"(fw), "v"(tv) : "memory");
    }
    // out stores AFTER arrival: drain overlaps the next step
    float* op = out + (size_t)t * (BATCH * DIM) + (size_t)erow * DIM + d0;
    *(float2*)op = make_float2(hn0, hn1);
    if (t == T_STEPS - 1) {
      float* fo = out + (size_t)T_STEPS * (BATCH * DIM) + (size_t)erow * DIM + d0;
      *(float2*)fo = make_float2(hn0, hn1);
    }
  }
}

extern "C" void kernel_launch(void* const* d_in, const int* in_sizes, int n_in,
                              void* d_out, int out_size, void* d_ws, size_t ws_size,
                              hipStream_t stream) {
  const float* inputs = (const float*)d_in[0];
  const float* Wxz = (const float*)d_in[1];
  const float* Whz = (const float*)d_in[2];
  const float* bz  = (const float*)d_in[3];
  const float* Wxr = (const float*)d_in[4];
  const float* Whr = (const float*)d_in[5];
  const float* br  = (const float*)d_in[6];
  const float* Wxh = (const float*)d_in[7];
  const float* Whh = (const float*)d_in[8];
  const float* bh  = (const float*)d_in[9];
  float* out = (float*)d_out;

  // ws layout: [0,4K) flags | [4K,8K) epoch | [8K,+256K) H dbuf | wpack 12.6MB | xbf 128MB
  char* ws = (char*)d_ws;
  u32* flags = (u32*)ws;
  u32* epoch = (u32*)(ws + 4096);
  u16* hglob = (u16*)(ws + 8192);
  u16* wpack = (u16*)(ws + 8192 + 2 * BATCH * DIM * sizeof(u16));
  size_t base_need = 8192 + 2 * BATCH * DIM * 2 + (size_t)NWG * 8 * NMAT * 8 * 64 * 8 * 2;
  size_t xbf_off = (base_need + 4095) & ~(size_t)4095;
  u32* xbf = (u32*)(ws + xbf_off);
  size_t xbf_bytes = (size_t)T_STEPS * BATCH * DIM * 2;
  bool use_xb = (ws_size >= xbf_off + xbf_bytes);
  if (ws_size < base_need) return;  // insufficient workspace: fail visibly

  hipLaunchKernelGGL(gru_init, dim3(1), dim3(1024), 0, stream, flags);
  const int total = NWG * 8 * NMAT * 8 * 64;
  hipLaunchKernelGGL(gru_pack, dim3((total + 255) / 256), dim3(256), 0, stream,
                     Wxz, Whz, Wxr, Whr, Wxh, Whh, wpack);
  if (use_xb) {
    hipLaunchKernelGGL(gru_xconv, dim3(T_STEPS * BATCH * DIM / 8 / 256), dim3(256), 0, stream,
                       inputs, xbf);
    hipLaunchKernelGGL(gru_scan<true>, dim3(NWG), dim3(NTHR), 0, stream,
                       inputs, xbf, bz, br, bh, wpack, hglob, flags, epoch, out);
  } else {
    hipLaunchKernelGGL(gru_scan<false>, dim3(NWG), dim3(NTHR), 0, stream,
                       inputs, xbf, bz, br, bh, wpack, hglob, flags, epoch, out);
  }
}